// Round 9
// baseline (151.836 us; speedup 1.0000x reference)
//
#include <hip/hip_runtime.h>
#include <stdint.h>

#define T_STEPS 100
#define BB 4
#define NN 512
#define KK 10
#define TBTOT (T_STEPS * BB)        // 400
#define LLT_ELT ((size_t)TBTOT * NN) // 204800 elements

typedef float f4 __attribute__((ext_vector_type(4)));

// ---------------- threefry2x32 (JAX-compatible, 20 rounds) ----------------
__device__ __forceinline__ uint32_t rotl32(uint32_t v, int d) {
  return (v << d) | (v >> (32 - d));
}

__device__ __forceinline__ void tf2x32(uint32_t k0, uint32_t k1,
                                       uint32_t& x0, uint32_t& x1) {
  uint32_t k2 = k0 ^ k1 ^ 0x1BD11BDAu;
  x0 += k0; x1 += k1;
#define TFR(r) { x0 += x1; x1 = rotl32(x1, r); x1 ^= x0; }
  TFR(13) TFR(15) TFR(26) TFR(6)   x0 += k1; x1 += k2 + 1u;
  TFR(17) TFR(29) TFR(16) TFR(24)  x0 += k2; x1 += k0 + 2u;
  TFR(13) TFR(15) TFR(26) TFR(6)   x0 += k0; x1 += k1 + 3u;
  TFR(17) TFR(29) TFR(16) TFR(24)  x0 += k1; x1 += k2 + 4u;
  TFR(13) TFR(15) TFR(26) TFR(6)   x0 += k2; x1 += k0 + 5u;
#undef TFR
}

__device__ __forceinline__ float bits_to_u01(uint32_t bits) {
  return __fsub_rn(__uint_as_float((bits >> 9) | 0x3f800000u), 1.0f);
}

// XLA ErfInv32 (Giles), w = -log((1-x)(1+x)) exactly as ElementalIrEmitter
__device__ __forceinline__ float erfinv_f32(float x) {
  float w = -logf(__fmul_rn(__fsub_rn(1.0f, x), __fadd_rn(1.0f, x)));
  float p;
  if (w < 5.0f) {
    w = __fsub_rn(w, 2.5f);
    p = 2.81022636e-08f;
    p = __fadd_rn(__fmul_rn(p, w), 3.43273939e-07f);
    p = __fadd_rn(__fmul_rn(p, w), -3.5233877e-06f);
    p = __fadd_rn(__fmul_rn(p, w), -4.39150654e-06f);
    p = __fadd_rn(__fmul_rn(p, w), 0.00021858087f);
    p = __fadd_rn(__fmul_rn(p, w), -0.00125372503f);
    p = __fadd_rn(__fmul_rn(p, w), -0.00417768164f);
    p = __fadd_rn(__fmul_rn(p, w), 0.246640727f);
    p = __fadd_rn(__fmul_rn(p, w), 1.50140941f);
  } else {
    w = __fsub_rn(sqrtf(w), 3.0f);
    p = -0.000200214257f;
    p = __fadd_rn(__fmul_rn(p, w), 0.000100950558f);
    p = __fadd_rn(__fmul_rn(p, w), 0.00134934322f);
    p = __fadd_rn(__fmul_rn(p, w), -0.00367342844f);
    p = __fadd_rn(__fmul_rn(p, w), 0.00573950773f);
    p = __fadd_rn(__fmul_rn(p, w), -0.0076224613f);
    p = __fadd_rn(__fmul_rn(p, w), 0.00943887047f);
    p = __fadd_rn(__fmul_rn(p, w), 1.00167406f);
    p = __fadd_rn(__fmul_rn(p, w), 2.83297682f);
  }
  return __fmul_rn(p, x);
}

// fast sigmoid: 1/(1+exp(-x)) via native exp + native rcp (~1-2 ulp)
__device__ __forceinline__ float fast_sigmoid(float x) {
  float e = __expf(-x);
  return __builtin_amdgcn_rcpf(__fadd_rn(1.0f, e));
}

// DPP-based partial butterfly stage: x += dpp(x)
template <int CTRL>
__device__ __forceinline__ float dpp_add(float x) {
  int v = __builtin_amdgcn_update_dpp(0, __float_as_int(x), CTRL, 0xF, 0xF, true);
  return __fadd_rn(x, __int_as_float(v));
}
__device__ __forceinline__ float readlane_f(float x, int lane) {
  return __int_as_float(__builtin_amdgcn_readlane(__float_as_int(x), lane));
}

// ---------------- Kernel A: softmax-mixture mean/std + L(f32) ---------------
__global__ void prep_kernel(const float* __restrict__ mu,
                            const float* __restrict__ sig,
                            const float* __restrict__ pi,
                            float* __restrict__ sm, float* __restrict__ ss,
                            float* __restrict__ Lf) {
  int m = blockIdx.x * blockDim.x + threadIdx.x;
  if (m >= BB * NN) return;
  const float* pp = pi + m * KK;
  float mx = pp[0];
  for (int k = 1; k < KK; k++) mx = fmaxf(mx, pp[k]);
  float e[KK]; float s = 0.0f;
  for (int k = 0; k < KK; k++) { e[k] = expf(__fsub_rn(pp[k], mx)); s = __fadd_rn(s, e[k]); }
  float smv = 0.0f, ssv = 0.0f, eps = 0.0f;
  for (int k = 0; k < KK; k++) {
    float p = e[k] / s;
    smv = __fadd_rn(smv, __fmul_rn(p, mu[m * KK + k]));
    ssv = __fadd_rn(ssv, __fmul_rn(p, sig[m * KK + k]));
    eps = __fadd_rn(eps, pp[k]);
  }
  sm[m] = smv; ss[m] = ssv;
  float ep = fminf(fmaxf(eps, 1e-8f), 1.0f);
  float lep = logf(ep);
  float l1 = logf(__fsub_rn(1.0f, ep));
  Lf[m] = (float)((double)lep - (double)l1);
}

// -------- Kernel B: JAX partitionable-threefry RNG -> pm table + uniforms ----
__global__ void rng_kernel(const float* __restrict__ sm,
                           const float* __restrict__ ss,
                           float* __restrict__ pm, float* __restrict__ uacc) {
  int id = blockIdx.x * blockDim.x + threadIdx.x;
  if (id >= T_STEPS * BB * NN) return;
  int t = id >> 11;        // /2048
  int m = id & 2047;       // b*512+n

  uint32_t kk0 = 0u, kk1 = (uint32_t)t;
  tf2x32(0u, 42u, kk0, kk1);
  uint32_t n0 = 0u, n1 = 0u; tf2x32(kk0, kk1, n0, n1);   // k_noise
  uint32_t y0 = 0u, y1 = (uint32_t)m;
  tf2x32(n0, n1, y0, y1);
  uint32_t bits = y0 ^ y1;

  float u01 = bits_to_u01(bits);
  const float lo = -0.99999994f;  // nextafter(-1,0) f32; span rounds to 2.0f
  float u = fmaxf(lo, __fadd_rn(__fmul_rn(u01, 2.0f), lo));
  float z = __fmul_rn(1.41421356237309515f, erfinv_f32(u));
  pm[id] = __fadd_rn(sm[m], __fmul_rn(z, ss[m]));

  if (m < 4) {
    uint32_t u0 = 0u, u1 = 1u; tf2x32(kk0, kk1, u0, u1); // k_unif
    uint32_t c0 = 0u, c1 = (uint32_t)m;
    tf2x32(u0, u1, c0, c1);
    uacc[t * 4 + m] = bits_to_u01(c0 ^ c1);
  }
}

// ------- Kernel C: partial llt[t][b][j] = sum_{i in chunk} sgm(pm_i pm_j)*L[b,i]
template <int SPLIT>
__global__ __launch_bounds__(512) void ll_kernel(const float* __restrict__ pm,
                                                 const float* __restrict__ Lf,
                                                 const float* __restrict__ A0,
                                                 float* __restrict__ llt_p,
                                                 float* __restrict__ ll0_p) {
  constexpr int CH = NN / SPLIT;
  __shared__ float spm[CH];
  __shared__ float sLc[CH];
  int j = threadIdx.x;
  int bi = blockIdx.x;
  if (bi < TBTOT * SPLIT) {
    int tb = bi / SPLIT;
    int s = bi - tb * SPLIT;
    int b = tb & 3;
    int i0 = s * CH;
    if (j < CH) {
      spm[j] = pm[tb * NN + i0 + j];
      sLc[j] = Lf[b * NN + i0 + j];
    }
    float pmj = pm[tb * NN + j];
    __syncthreads();
    double acc = 0.0;
    #pragma unroll 8
    for (int i = 0; i < CH; i += 2) {
      float x0 = __fmul_rn(spm[i], pmj);
      float x1 = __fmul_rn(spm[i + 1], pmj);
      float t0 = __fmul_rn(fast_sigmoid(x0), sLc[i]);
      float t1 = __fmul_rn(fast_sigmoid(x1), sLc[i + 1]);
      acc += (double)__fadd_rn(t0, t1);
    }
    llt_p[(size_t)s * LLT_ELT + (size_t)tb * NN + j] = (float)acc;
  } else {
    int bi2 = bi - TBTOT * SPLIT;
    int b = bi2 / SPLIT;
    int s = bi2 - b * SPLIT;
    int i0 = s * CH;
    if (j < CH) sLc[j] = Lf[b * NN + i0 + j];
    __syncthreads();
    double acc = 0.0;
    #pragma unroll 4
    for (int i = 0; i < CH; i++) {
      acc += (double)A0[(size_t)(i0 + i) * NN + j] * (double)sLc[i];
    }
    ll0_p[s * (BB * NN) + b * NN + j] = (float)acc;
  }
}

// ------- Kernel C2: deterministic combine of f32 partials (f64 sum) ---------
template <int SPLIT>
__global__ __launch_bounds__(512) void combine_kernel(const float* __restrict__ llt_p,
                                                      const float* __restrict__ ll0_p,
                                                      float* __restrict__ llt,
                                                      float* __restrict__ ll0) {
  int bi = blockIdx.x;
  int j = threadIdx.x;
  if (bi < T_STEPS) {
    #pragma unroll
    for (int b = 0; b < BB; b++) {
      size_t idx = ((size_t)bi * BB + b) * NN + j;
      double a = (double)llt_p[idx];
      #pragma unroll
      for (int s = 1; s < SPLIT; s++) a += (double)llt_p[(size_t)s * LLT_ELT + idx];
      llt[idx] = (float)a;
    }
  } else {
    #pragma unroll
    for (int b = 0; b < BB; b++) {
      int idx = b * NN + j;
      double a = (double)ll0_p[idx];
      #pragma unroll
      for (int s = 1; s < SPLIT; s++) a += (double)ll0_p[s * (BB * NN) + idx];
      ll0[idx] = (float)a;
    }
  }
}

// ------- Kernel D: chain with LDS-ring DMA prefetch + hand-counted vmcnt ----
// Single wave.  llt rows stream via global_load_lds into a 5-slot LDS ring,
// 4 chunks (steps) in flight; per-step wait = vmcnt(24) only (chunk t's 8
// DMAs), younger chunks stay in flight ACROSS steps.  No compiler-tracked
// VMEM in the loop -> no conservative drains.  ds_read_b128 slot reads are
// conflict-free (contiguous 1KB rows).
#define SLOTS 5
#define CHUNK_F 2048   // floats per chunk (8KB = one step: 4 batches x 512)

#define WAITV(n) { asm volatile("s_waitcnt vmcnt(" #n ")" ::: "memory"); \
                   __builtin_amdgcn_sched_barrier(0); }

__device__ __forceinline__ void issue_chunk(const float* __restrict__ llt,
                                            float* lds_slot, int T, int g) {
  #pragma unroll
  for (int v = 0; v < 8; v++) {
    const float* src = llt + ((size_t)T * 8 + v) * 256 + g * 4;
    float* dst = lds_slot + v * 256;   // wave-uniform base; HW adds lane*16B
    __builtin_amdgcn_global_load_lds(
        (const __attribute__((address_space(1))) void*)src,
        (__attribute__((address_space(3))) void*)dst, 16, 0, 0);
  }
}

#define CH_READ(BUF, SLOT)                                                   \
  {                                                                          \
    _Pragma("unroll")                                                        \
    for (int v = 0; v < 8; v++)                                              \
      BUF[v] = *(const f4*)&lring[SLOT][v * 256 + 4 * g];                    \
  }

#define CH_ACC2(BUF, B)                                                      \
  {                                                                          \
    _Pragma("unroll")                                                        \
    for (int k = 0; k < 2; k++) {                                            \
      _Pragma("unroll")                                                      \
      for (int c = 0; c < 4; c++)                                            \
        C[k][c] += (double)BUF[B * 2 + k][c] - (double)cur[B][k][c];         \
      cur[B][k] = BUF[B * 2 + k];                                            \
    }                                                                        \
  }

#define CH_STEP2(BUF, T)                                                     \
  {                                                                          \
    float4 ua = sua[T];                                                      \
    float ps = 0.0f;                                                         \
    _Pragma("unroll")                                                        \
    for (int k = 0; k < 2; k++) {                                            \
      _Pragma("unroll")                                                      \
      for (int c = 0; c < 4; c++) {                                          \
        double ts = ((double)BUF[0 * 2 + k][c] + (double)BUF[1 * 2 + k][c]) +\
                    ((double)BUF[2 * 2 + k][c] + (double)BUF[3 * 2 + k][c]); \
        float e = fminf(__expf((float)(ts - C[k][c])), 1.0f);                \
        ps = __fadd_rn(ps, e);                                               \
      }                                                                      \
    }                                                                        \
    ps = dpp_add<0xB1>(ps);   /* xor1 */                                     \
    ps = dpp_add<0x4E>(ps);   /* xor2 */                                     \
    ps = dpp_add<0x141>(ps);  /* half-mirror */                              \
    ps = dpp_add<0x140>(ps);  /* mirror */                                   \
    float s0 = readlane_f(ps, 0), s1 = readlane_f(ps, 16);                   \
    float s2 = readlane_f(ps, 32), s3 = readlane_f(ps, 48);                  \
    float tot = __fadd_rn(__fadd_rn(s0, s1), __fadd_rn(s2, s3));             \
    float ratio = __fmul_rn(tot, 1.0f / 512.0f);                             \
    if (ua.x < ratio) { st.x = (T); CH_ACC2(BUF, 0) }                        \
    if (ua.y < ratio) { st.y = (T); CH_ACC2(BUF, 1) }                        \
    if (ua.z < ratio) { st.z = (T); CH_ACC2(BUF, 2) }                        \
    if (ua.w < ratio) { st.w = (T); CH_ACC2(BUF, 3) }                        \
    sst[T] = st;                                                             \
  }

__global__ __launch_bounds__(64) void chain_kernel(const float* __restrict__ llt,
                                                   const float* __restrict__ ll0,
                                                   const float* __restrict__ uacc,
                                                   int* __restrict__ counts) {
  __shared__ float lring[SLOTS][CHUNK_F];   // 40 KB ring
  __shared__ float4 sua[T_STEPS];
  __shared__ int4 sst[T_STEPS];
  __shared__ int scnt[BB * (T_STEPS + 1)];
  int g = threadIdx.x;

  // --- all compiler-tracked VMEM happens BEFORE the DMA ring starts ---
  const float4* uacc4 = (const float4*)uacc;
  for (int t = g; t < T_STEPS; t += 64) sua[t] = uacc4[t];

  const f4* ll04 = (const f4*)ll0;
  f4 cur[4][2];
  #pragma unroll
  for (int b = 0; b < 4; b++)
    #pragma unroll
    for (int k = 0; k < 2; k++) cur[b][k] = ll04[(b * 2 + k) * 64 + g];
  double C[2][4];
  #pragma unroll
  for (int k = 0; k < 2; k++)
    #pragma unroll
    for (int c = 0; c < 4; c++)
      C[k][c] = ((double)cur[0][k][c] + (double)cur[1][k][c]) +
                ((double)cur[2][k][c] + (double)cur[3][k][c]);
  int4 st = make_int4(-1, -1, -1, -1);
  // force retirement of the loads above before the ring starts
  asm volatile("s_waitcnt vmcnt(0)" ::: "memory");

  // --- prologue: fill 4 chunks ---
  issue_chunk(llt, &lring[0][0], 0, g);
  issue_chunk(llt, &lring[1][0], 1, g);
  issue_chunk(llt, &lring[2][0], 2, g);
  issue_chunk(llt, &lring[3][0], 3, g);

  f4 B[8];
  for (int t = 0; t < 96; t++) {
    WAITV(24)                       // chunk t's 8 DMAs retired; t+1..t+3 in flight
    int slot = t % SLOTS;
    CH_READ(B, slot)
    issue_chunk(llt, &lring[(t + 4) % SLOTS][0], t + 4, g);
    CH_STEP2(B, t)
  }
  { WAITV(24) CH_READ(B, 96 % SLOTS) CH_STEP2(B, 96) }
  { WAITV(16) CH_READ(B, 97 % SLOTS) CH_STEP2(B, 97) }
  { WAITV(8)  CH_READ(B, 98 % SLOTS) CH_STEP2(B, 98) }
  { WAITV(0)  CH_READ(B, 99 % SLOTS) CH_STEP2(B, 99) }

  __syncthreads();
  for (int s = g; s < BB * (T_STEPS + 1); s += 64) scnt[s] = 0;
  __syncthreads();
  for (int t = g; t < T_STEPS; t += 64) {
    int4 s4 = sst[t];
    atomicAdd(&scnt[0 * (T_STEPS + 1) + s4.x + 1], 1);
    atomicAdd(&scnt[1 * (T_STEPS + 1) + s4.y + 1], 1);
    atomicAdd(&scnt[2 * (T_STEPS + 1) + s4.z + 1], 1);
    atomicAdd(&scnt[3 * (T_STEPS + 1) + s4.w + 1], 1);
  }
  __syncthreads();
  for (int s = g; s < BB * (T_STEPS + 1); s += 64) counts[s] = scnt[s];
}

// ---------------- Kernel E: acc = sum_states count * A_state / num_samples --
__global__ __launch_bounds__(512) void out_kernel(const float* __restrict__ pm,
                                                  const float* __restrict__ A0,
                                                  const int* __restrict__ counts,
                                                  float* __restrict__ out) {
  __shared__ int scnt[T_STEPS + 1];
  int b = blockIdx.x >> 9;
  int i = blockIdx.x & 511;
  int j = threadIdx.x;
  if (j < T_STEPS + 1) scnt[j] = counts[b * (T_STEPS + 1) + j];
  __syncthreads();
  float r = (float)scnt[0] * A0[(size_t)i * NN + j];
  #pragma unroll 4
  for (int t = 0; t < T_STEPS; t++) {
    int c = scnt[t + 1];
    if (c) {
      float x = __fmul_rn(pm[(size_t)(t * BB + b) * NN + i],
                          pm[(size_t)(t * BB + b) * NN + j]);
      r += (float)c * fast_sigmoid(x);
    }
  }
  out[((size_t)b * NN + i) * NN + j] = r * 0.01f;
}

extern "C" void kernel_launch(void* const* d_in, const int* in_sizes, int n_in,
                              void* d_out, int out_size, void* d_ws, size_t ws_size,
                              hipStream_t stream) {
  const float* mu  = (const float*)d_in[0];
  const float* sig = (const float*)d_in[1];
  const float* pi  = (const float*)d_in[2];
  const float* A0  = (const float*)d_in[3];

  char* ws = (char*)d_ws;
  size_t off = 0;
  auto alloc = [&](size_t bytes) -> char* {
    char* p = ws + off;
    off += (bytes + 255) & ~(size_t)255;
    return p;
  };
  float* llt  = (float*)alloc(LLT_ELT * 4);            // 819,200
  float* ll0  = (float*)alloc(BB * NN * 4);            // 8,192
  float* pm   = (float*)alloc(LLT_ELT * 4);            // 819,200
  float* Lf   = (float*)alloc(BB * NN * 4);
  float* sm   = (float*)alloc(BB * NN * 4);
  float* ssv  = (float*)alloc(BB * NN * 4);
  float* uacc = (float*)alloc(T_STEPS * 4 * 4);
  int*   cnts = (int*)alloc(BB * (T_STEPS + 1) * 4);
  size_t fixed_end = off;
  float* outp = (float*)d_out;

  // choose SPLIT by available scratch for partial buffers (f32)
  size_t part4 = 4 * LLT_ELT * 4 + 4 * BB * NN * 4 + 1024;
  size_t part2 = 2 * LLT_ELT * 4 + 2 * BB * NN * 4 + 1024;
  int split = (ws_size >= fixed_end + part4) ? 4
            : (ws_size >= fixed_end + part2) ? 2 : 1;

  float* llt_p;
  float* ll0_p;
  if (split > 1) {
    llt_p = (float*)alloc((size_t)split * LLT_ELT * 4);
    ll0_p = (float*)alloc((size_t)split * BB * NN * 4);
  } else {
    llt_p = llt;
    ll0_p = ll0;
  }

  prep_kernel<<<8, 256, 0, stream>>>(mu, sig, pi, sm, ssv, Lf);
  rng_kernel<<<(T_STEPS * BB * NN + 255) / 256, 256, 0, stream>>>(sm, ssv, pm, uacc);
  if (split == 4) {
    ll_kernel<4><<<(TBTOT + BB) * 4, 512, 0, stream>>>(pm, Lf, A0, llt_p, ll0_p);
    combine_kernel<4><<<T_STEPS + 1, 512, 0, stream>>>(llt_p, ll0_p, llt, ll0);
  } else if (split == 2) {
    ll_kernel<2><<<(TBTOT + BB) * 2, 512, 0, stream>>>(pm, Lf, A0, llt_p, ll0_p);
    combine_kernel<2><<<T_STEPS + 1, 512, 0, stream>>>(llt_p, ll0_p, llt, ll0);
  } else {
    ll_kernel<1><<<TBTOT + BB, 512, 0, stream>>>(pm, Lf, A0, llt_p, ll0_p);
  }
  chain_kernel<<<1, 64, 0, stream>>>(llt, ll0, uacc, cnts);
  out_kernel<<<BB * NN, 512, 0, stream>>>(pm, A0, cnts, outp);
}

// Round 11
// 145.347 us; speedup vs baseline: 1.0446x; 1.0446x over previous
//
#include <hip/hip_runtime.h>
#include <stdint.h>

#define T_STEPS 100
#define BB 4
#define NN 512
#define KK 10
#define LOG2E 1.4426950408889634

typedef float f4 __attribute__((ext_vector_type(4)));

// ---------------- threefry2x32 (JAX-compatible, 20 rounds) ----------------
__device__ __forceinline__ uint32_t rotl32(uint32_t v, int d) {
  return (v << d) | (v >> (32 - d));
}

__device__ __forceinline__ void tf2x32(uint32_t k0, uint32_t k1,
                                       uint32_t& x0, uint32_t& x1) {
  uint32_t k2 = k0 ^ k1 ^ 0x1BD11BDAu;
  x0 += k0; x1 += k1;
#define TFR(r) { x0 += x1; x1 = rotl32(x1, r); x1 ^= x0; }
  TFR(13) TFR(15) TFR(26) TFR(6)   x0 += k1; x1 += k2 + 1u;
  TFR(17) TFR(29) TFR(16) TFR(24)  x0 += k2; x1 += k0 + 2u;
  TFR(13) TFR(15) TFR(26) TFR(6)   x0 += k0; x1 += k1 + 3u;
  TFR(17) TFR(29) TFR(16) TFR(24)  x0 += k1; x1 += k2 + 4u;
  TFR(13) TFR(15) TFR(26) TFR(6)   x0 += k2; x1 += k0 + 5u;
#undef TFR
}

__device__ __forceinline__ float bits_to_u01(uint32_t bits) {
  return __fsub_rn(__uint_as_float((bits >> 9) | 0x3f800000u), 1.0f);
}

// XLA ErfInv32 (Giles)
__device__ __forceinline__ float erfinv_f32(float x) {
  float w = -logf(__fmul_rn(__fsub_rn(1.0f, x), __fadd_rn(1.0f, x)));
  float p;
  if (w < 5.0f) {
    w = __fsub_rn(w, 2.5f);
    p = 2.81022636e-08f;
    p = __fadd_rn(__fmul_rn(p, w), 3.43273939e-07f);
    p = __fadd_rn(__fmul_rn(p, w), -3.5233877e-06f);
    p = __fadd_rn(__fmul_rn(p, w), -4.39150654e-06f);
    p = __fadd_rn(__fmul_rn(p, w), 0.00021858087f);
    p = __fadd_rn(__fmul_rn(p, w), -0.00125372503f);
    p = __fadd_rn(__fmul_rn(p, w), -0.00417768164f);
    p = __fadd_rn(__fmul_rn(p, w), 0.246640727f);
    p = __fadd_rn(__fmul_rn(p, w), 1.50140941f);
  } else {
    w = __fsub_rn(sqrtf(w), 3.0f);
    p = -0.000200214257f;
    p = __fadd_rn(__fmul_rn(p, w), 0.000100950558f);
    p = __fadd_rn(__fmul_rn(p, w), 0.00134934322f);
    p = __fadd_rn(__fmul_rn(p, w), -0.00367342844f);
    p = __fadd_rn(__fmul_rn(p, w), 0.00573950773f);
    p = __fadd_rn(__fmul_rn(p, w), -0.0076224613f);
    p = __fadd_rn(__fmul_rn(p, w), 0.00943887047f);
    p = __fadd_rn(__fmul_rn(p, w), 1.00167406f);
    p = __fadd_rn(__fmul_rn(p, w), 2.83297682f);
  }
  return __fmul_rn(p, x);
}

// fast sigmoid: 1/(1+exp(-x)) via native exp + native rcp
__device__ __forceinline__ float fast_sigmoid(float x) {
  float e = __expf(-x);
  return __builtin_amdgcn_rcpf(__fadd_rn(1.0f, e));
}

template <int CTRL>
__device__ __forceinline__ float dpp_add(float x) {
  int v = __builtin_amdgcn_update_dpp(0, __float_as_int(x), CTRL, 0xF, 0xF, true);
  return __fadd_rn(x, __int_as_float(v));
}

// ------ Kernel B: RNG + merged prep (per-thread softmax recompute) ----------
__global__ void rng_kernel(const float* __restrict__ mu,
                           const float* __restrict__ sig,
                           const float* __restrict__ pi,
                           float* __restrict__ pm, float* __restrict__ uacc,
                           float* __restrict__ Lf) {
  int id = blockIdx.x * blockDim.x + threadIdx.x;
  if (id >= T_STEPS * BB * NN) return;
  int t = id >> 11;        // /2048
  int m = id & 2047;       // b*512+n

  // --- prep (identical rounding to the verified prep_kernel) ---
  const float* pp = pi + m * KK;
  float mx = pp[0];
  for (int k = 1; k < KK; k++) mx = fmaxf(mx, pp[k]);
  float e[KK]; float s = 0.0f;
  for (int k = 0; k < KK; k++) { e[k] = expf(__fsub_rn(pp[k], mx)); s = __fadd_rn(s, e[k]); }
  float smv = 0.0f, ssv = 0.0f, eps = 0.0f;
  for (int k = 0; k < KK; k++) {
    float p = e[k] / s;
    smv = __fadd_rn(smv, __fmul_rn(p, mu[m * KK + k]));
    ssv = __fadd_rn(ssv, __fmul_rn(p, sig[m * KK + k]));
    eps = __fadd_rn(eps, pp[k]);
  }
  if (t == 0) {
    float ep = fminf(fmaxf(eps, 1e-8f), 1.0f);
    float lep = logf(ep);
    float l1 = logf(__fsub_rn(1.0f, ep));
    Lf[m] = (float)((double)lep - (double)l1);
  }

  // --- partitionable threefry ---
  uint32_t kk0 = 0u, kk1 = (uint32_t)t;
  tf2x32(0u, 42u, kk0, kk1);
  uint32_t n0 = 0u, n1 = 0u; tf2x32(kk0, kk1, n0, n1);   // k_noise
  uint32_t y0 = 0u, y1 = (uint32_t)m;
  tf2x32(n0, n1, y0, y1);
  uint32_t bits = y0 ^ y1;

  float u01 = bits_to_u01(bits);
  const float lo = -0.99999994f;
  float u = fmaxf(lo, __fadd_rn(__fmul_rn(u01, 2.0f), lo));
  float z = __fmul_rn(1.41421356237309515f, erfinv_f32(u));
  pm[id] = __fadd_rn(smv, __fmul_rn(z, ssv));

  if (m < 4) {
    uint32_t u0 = 0u, u1 = 1u; tf2x32(kk0, kk1, u0, u1); // k_unif
    uint32_t c0 = 0u, c1 = (uint32_t)m;
    tf2x32(u0, u1, c0, c1);
    uacc[t * 4 + m] = __fmul_rn(bits_to_u01(c0 ^ c1), 512.0f);  // pre-x512 (exact)
  }
}

// ------ Kernel C: llt (final, log2e-scaled f32) — j-chunk tiling, no combine -
__global__ __launch_bounds__(512) void ll_kernel(const float* __restrict__ pm,
                                                 const float* __restrict__ Lf,
                                                 const float* __restrict__ A0,
                                                 float* __restrict__ llt,
                                                 float* __restrict__ ll0) {
  __shared__ float spm[NN];
  __shared__ float sLc[NN];
  __shared__ double pt[4][128];
  int tid = threadIdx.x;
  int q = tid >> 7, jj = tid & 127;
  int bi = blockIdx.x;
  if (bi < 1600) {
    int tb = bi >> 2, jc = bi & 3;
    int b = tb & 3;
    spm[tid] = pm[tb * NN + tid];
    sLc[tid] = Lf[b * NN + tid];
    __syncthreads();
    int j = jc * 128 + jj;
    float pmj = spm[j];
    int i0 = q * 128;
    double acc = 0.0;
    #pragma unroll 8
    for (int i = 0; i < 128; i += 2) {
      float x0 = __fmul_rn(spm[i0 + i], pmj);
      float x1 = __fmul_rn(spm[i0 + i + 1], pmj);
      float t0 = __fmul_rn(fast_sigmoid(x0), sLc[i0 + i]);
      float t1 = __fmul_rn(fast_sigmoid(x1), sLc[i0 + i + 1]);
      acc += (double)__fadd_rn(t0, t1);
    }
    pt[q][jj] = acc;
    __syncthreads();
    if (tid < 128) {
      double a = ((pt[0][jj] + pt[1][jj]) + pt[2][jj]) + pt[3][jj];
      llt[tb * NN + jc * 128 + jj] = (float)(a * LOG2E);
    }
  } else {
    int idx = bi - 1600;
    int b = idx >> 2, jc = idx & 3;
    sLc[tid] = Lf[b * NN + tid];
    __syncthreads();
    int j = jc * 128 + jj;
    int i0 = q * 128;
    double acc = 0.0;
    #pragma unroll 4
    for (int i = 0; i < 128; i++) {
      acc += (double)A0[(size_t)(i0 + i) * NN + j] * (double)sLc[i0 + i];
    }
    pt[q][jj] = acc;
    __syncthreads();
    if (tid < 128) {
      double a = ((pt[0][jj] + pt[1][jj]) + pt[2][jj]) + pt[3][jj];
      ll0[b * NN + jc * 128 + jj] = (float)(a * LOG2E);
    }
  }
}

// ------- Kernel D: lean f32 single-wave chain ------------------------------
// lane g owns j = k*256 + 4g + c (k=0..1, c=0..3).  Rows pre-scaled by
// log2(e) -> exp is a single v_exp_f32 (exp2f).  Reduce: 4 DPP +
// ds_swizzle(xor16) + ds_bpermute(xor32) == verified ((r0+r1)+(r2+r3)) tree.
// u pre-scaled x512 (exact equivalence with ratio = tot/512).
// History: lane-uniform packed state word -> LDS spk[T] (lane 0 store).
#define CH_LOAD(P, T)                                                        \
  {                                                                          \
    _Pragma("unroll")                                                        \
    for (int b = 0; b < 4; b++) {                                            \
      _Pragma("unroll")                                                      \
      for (int k = 0; k < 2; k++)                                            \
        P[b * 2 + k] = lltv[((size_t)(T) * 4 + b) * 128 + k * 64 + g];       \
    }                                                                        \
  }

#define CH_STEP(P, T)                                                        \
  {                                                                          \
    float4 ua = uaccv[T];                                                    \
    f4 tp0 = (P[0] + P[2]) + (P[4] + P[6]);                                  \
    f4 tp1 = (P[1] + P[3]) + (P[5] + P[7]);                                  \
    f4 d0 = tp0 - S0;                                                        \
    f4 d1 = tp1 - S1;                                                        \
    f4 E0, E1;                                                               \
    _Pragma("unroll")                                                        \
    for (int c = 0; c < 4; c++) {                                            \
      E0[c] = fminf(exp2f(d0[c]), 1.0f);                                     \
      E1[c] = fminf(exp2f(d1[c]), 1.0f);                                     \
    }                                                                        \
    f4 Es = E0 + E1;                                                         \
    float ps = __fadd_rn(__fadd_rn(Es[0], Es[1]), __fadd_rn(Es[2], Es[3]));  \
    ps = dpp_add<0xB1>(ps);   /* xor1 */                                     \
    ps = dpp_add<0x4E>(ps);   /* xor2 */                                     \
    ps = dpp_add<0x141>(ps);  /* xor4 (half-mirror) */                       \
    ps = dpp_add<0x140>(ps);  /* xor8 (mirror) */                            \
    ps = __fadd_rn(ps, __int_as_float(__builtin_amdgcn_ds_swizzle(           \
             __float_as_int(ps), 0x401F)));  /* xor16 */                     \
    ps = __fadd_rn(ps, __int_as_float(__builtin_amdgcn_ds_bpermute(          \
             lx32, __float_as_int(ps))));    /* xor32 */                     \
    if (ua.x < ps) { st0 = (T); cur[0] = P[0]; cur[1] = P[1]; }              \
    if (ua.y < ps) { st1 = (T); cur[2] = P[2]; cur[3] = P[3]; }              \
    if (ua.z < ps) { st2 = (T); cur[4] = P[4]; cur[5] = P[5]; }              \
    if (ua.w < ps) { st3 = (T); cur[6] = P[6]; cur[7] = P[7]; }              \
    S0 = (cur[0] + cur[2]) + (cur[4] + cur[6]);                              \
    S1 = (cur[1] + cur[3]) + (cur[5] + cur[7]);                              \
    if (g == 0) {                                                            \
      uint32_t pk = (uint32_t)(st0 + 1) | ((uint32_t)(st1 + 1) << 8) |       \
                    ((uint32_t)(st2 + 1) << 16) | ((uint32_t)(st3 + 1) << 24);\
      spk[T] = pk;                                                           \
    }                                                                        \
  }

__global__ __launch_bounds__(64, 1) void chain_kernel(const float* __restrict__ llt,
                                                      const float* __restrict__ ll0,
                                                      const float* __restrict__ uacc,
                                                      int* __restrict__ slist,
                                                      float* __restrict__ wlist,
                                                      int* __restrict__ Mv) {
  __shared__ uint32_t spk[T_STEPS];
  __shared__ int scnt[BB][101];
  int g = threadIdx.x;
  int lx32 = (g ^ 32) << 2;

  const f4* lltv = (const f4*)llt;
  const f4* ll0v = (const f4*)ll0;
  const float4* uaccv = (const float4*)uacc;

  f4 cur[8];
  #pragma unroll
  for (int b = 0; b < 4; b++)
    #pragma unroll
    for (int k = 0; k < 2; k++) cur[b * 2 + k] = ll0v[b * 128 + k * 64 + g];
  f4 S0 = (cur[0] + cur[2]) + (cur[4] + cur[6]);
  f4 S1 = (cur[1] + cur[3]) + (cur[5] + cur[7]);
  int st0 = -1, st1 = -1, st2 = -1, st3 = -1;

  f4 Pa[8], Pb[8], Pc[8];
  CH_LOAD(Pa, 0)
  CH_LOAD(Pb, 1)
  CH_LOAD(Pc, 2)

  for (int t = 0; t < 99; t += 3) {
    CH_STEP(Pa, t)
    if (t + 3 < T_STEPS) CH_LOAD(Pa, t + 3)
    CH_STEP(Pb, t + 1)
    if (t + 4 < T_STEPS) CH_LOAD(Pb, t + 4)
    CH_STEP(Pc, t + 2)
    if (t + 5 < T_STEPS) CH_LOAD(Pc, t + 5)
  }
  CH_STEP(Pa, 99)

  // ---- epilogue: histogram + compacted (state, weight) list ----
  __syncthreads();  // single wave: orders spk stores before reads (cheap)
  for (int s = g; s < BB * 101; s += 64) (&scnt[0][0])[s] = 0;
  __syncthreads();
  {
    uint32_t p0 = spk[g];           // step g
    atomicAdd(&scnt[0][p0 & 255], 1);
    atomicAdd(&scnt[1][(p0 >> 8) & 255], 1);
    atomicAdd(&scnt[2][(p0 >> 16) & 255], 1);
    atomicAdd(&scnt[3][p0 >> 24], 1);
    if (g < T_STEPS - 64) {
      uint32_t p1 = spk[64 + g];    // step 64+g
      atomicAdd(&scnt[0][p1 & 255], 1);
      atomicAdd(&scnt[1][(p1 >> 8) & 255], 1);
      atomicAdd(&scnt[2][(p1 >> 16) & 255], 1);
      atomicAdd(&scnt[3][p1 >> 24], 1);
    }
  }
  __syncthreads();
  if (g < 4) {
    int m = 0;
    for (int s = 0; s <= 100; s++) {
      int c = scnt[g][s];
      if (c) { slist[g * 104 + m] = s; wlist[g * 104 + m] = (float)c; m++; }
    }
    Mv[g] = m;
  }
}

// ---------------- Kernel E: out via compacted state list --------------------
__global__ __launch_bounds__(512) void out_kernel(const float* __restrict__ pm,
                                                  const float* __restrict__ A0,
                                                  const int* __restrict__ slist,
                                                  const float* __restrict__ wlist,
                                                  const int* __restrict__ Mv,
                                                  float* __restrict__ out) {
  int b = blockIdx.x >> 9;
  int i = blockIdx.x & 511;
  int j = threadIdx.x;
  int M = Mv[b];
  float r = 0.0f;
  for (int e = 0; e < M; e++) {
    int s = slist[b * 104 + e];
    float w = wlist[b * 104 + e];
    if (s == 0) {
      r += w * A0[(size_t)i * NN + j];
    } else {
      int t = s - 1;
      float pmi = pm[(size_t)(t * BB + b) * NN + i];
      float pmj = pm[(size_t)(t * BB + b) * NN + j];
      r += w * fast_sigmoid(__fmul_rn(pmi, pmj));
    }
  }
  out[((size_t)b * NN + i) * NN + j] = r * 0.01f;
}

extern "C" void kernel_launch(void* const* d_in, const int* in_sizes, int n_in,
                              void* d_out, int out_size, void* d_ws, size_t ws_size,
                              hipStream_t stream) {
  const float* mu  = (const float*)d_in[0];
  const float* sig = (const float*)d_in[1];
  const float* pi  = (const float*)d_in[2];
  const float* A0  = (const float*)d_in[3];

  char* ws = (char*)d_ws;
  size_t off = 0;
  auto alloc = [&](size_t bytes) -> char* {
    char* p = ws + off;
    off += (bytes + 255) & ~(size_t)255;
    return p;
  };
  float* llt   = (float*)alloc((size_t)T_STEPS * BB * NN * 4); // 819,200
  float* ll0   = (float*)alloc(BB * NN * 4);                   // 8,192
  float* pm    = (float*)alloc((size_t)T_STEPS * BB * NN * 4); // 819,200
  float* Lf    = (float*)alloc(BB * NN * 4);
  float* uacc  = (float*)alloc(T_STEPS * 4 * 4);
  int*   slist = (int*)alloc(BB * 104 * 4);
  float* wlist = (float*)alloc(BB * 104 * 4);
  int*   Mv    = (int*)alloc(4 * 4);
  float* outp  = (float*)d_out;

  rng_kernel<<<(T_STEPS * BB * NN + 255) / 256, 256, 0, stream>>>(mu, sig, pi,
                                                                  pm, uacc, Lf);
  ll_kernel<<<1616, 512, 0, stream>>>(pm, Lf, A0, llt, ll0);
  chain_kernel<<<1, 64, 0, stream>>>(llt, ll0, uacc, slist, wlist, Mv);
  out_kernel<<<BB * NN, 512, 0, stream>>>(pm, A0, slist, wlist, Mv, outp);
}